// Round 7
// baseline (235.325 us; speedup 1.0000x reference)
//
#include <hip/hip_runtime.h>
#include <hip/hip_bf16.h>
#include <math.h>

typedef unsigned short ushort_t;
typedef __attribute__((ext_vector_type(8))) short bf16x8;
typedef __attribute__((ext_vector_type(4))) float f32x4;

constexpr int BATCH   = 4;
constexpr int LEN_IN  = 5440;
constexpr int LEN_Q   = 5440;
constexpr int M_TOT   = BATCH * LEN_Q;   // 21760

__device__ __forceinline__ ushort_t bfbits(float x) {
    __hip_bfloat16 h = __float2bfloat16(x);
    ushort_t u; __builtin_memcpy(&u, &h, 2); return u;
}
__device__ __forceinline__ unsigned pk2(float a, float b) {
    return (unsigned)bfbits(a) | ((unsigned)bfbits(b) << 16);
}

// ======================= weight pack / transpose (tiny) =======================
__global__ __launch_bounds__(256) void pack_w(
    const float* __restrict__ Wv, const float* __restrict__ Wo,
    const float* __restrict__ Wa, const float* __restrict__ Wout,
    const float* __restrict__ b_off, const float* __restrict__ b_attn,
    ushort_t* __restrict__ wvT, ushort_t* __restrict__ woaT,
    ushort_t* __restrict__ woutT, float* __restrict__ bias_oa)
{
    const int blk = blockIdx.x, tid = threadIdx.x;
    if (blk < 64) {
        const float* src = (blk < 32) ? Wv : Wout;
        ushort_t*    dst = (blk < 32) ? wvT : woutT;
        const int base = (blk & 31) * 2048;
#pragma unroll
        for (int i = 0; i < 8; i++) {
            const int idx = base + i * 256 + tid;
            const int k = idx >> 8, n = idx & 255;
            dst[n * 256 + k] = bfbits(src[idx]);
        }
    } else if (blk < 112) {
        const int base = (blk - 64) * 2048;
#pragma unroll
        for (int i = 0; i < 8; i++) {
            const int idx = base + i * 256 + tid;   // < 98304
            const int k = idx / 384, j = idx - k * 384;
            const float v = (j < 256) ? Wo[k * 256 + j] : Wa[k * 128 + (j - 256)];
            woaT[j * 256 + k] = bfbits(v);
        }
    } else {
        bias_oa[tid] = b_off[tid];
        if (tid < 128) bias_oa[256 + tid] = b_attn[tid];
    }
}

// ======================= value GEMM =======================
// value_bf[M,256](bf16) = in_flat[M,256](f32) @ wvT[256n][256k]^T + b_val
// 680 blocks = 170 m-chunks(128 rows) x 4 n-strips(64 cols). 256 thr = 4 waves;
// wave w handles rows [w*32, w*32+32) of the chunk as 2 m-tiles of 16.
__global__ __launch_bounds__(256) void gemm_value(
    const float* __restrict__ A, const ushort_t* __restrict__ wvT,
    const float* __restrict__ b_val, ushort_t* __restrict__ C)
{
    __shared__ float sw_all[4 * 16 * 68];
    const int tid = threadIdx.x;
    const int wave = tid >> 6, lane = tid & 63;
    const int row16 = lane & 15, kg8 = (lane >> 4) * 8, rb4 = (lane >> 4) * 4;
    const int strip = blockIdx.x & 3;          // n-strip (64 cols)
    const int chunk = blockIdx.x >> 2;         // m-chunk (128 rows)
    const int n0 = strip * 64;
    const int r0 = chunk * 128 + wave * 32;    // this wave's first row

    f32x4 acc[2][4] = {};
#pragma unroll
    for (int kt = 0; kt < 8; kt++) {
        bf16x8 af[2];
#pragma unroll
        for (int mt = 0; mt < 2; mt++) {
            const float* ap = A + (size_t)(r0 + mt * 16 + row16) * 256 + kt * 32 + kg8;
            float4 f0 = *(const float4*)(ap);
            float4 f1 = *(const float4*)(ap + 4);
            uint4 u;
            u.x = pk2(f0.x, f0.y); u.y = pk2(f0.z, f0.w);
            u.z = pk2(f1.x, f1.y); u.w = pk2(f1.z, f1.w);
            __builtin_memcpy(&af[mt], &u, 16);
        }
#pragma unroll
        for (int nt = 0; nt < 4; nt++) {
            bf16x8 bfv = *(const bf16x8*)(wvT + (size_t)(n0 + nt * 16 + row16) * 256
                                              + kt * 32 + kg8);
#pragma unroll
            for (int mt = 0; mt < 2; mt++)
                acc[mt][nt] = __builtin_amdgcn_mfma_f32_16x16x32_bf16(
                    af[mt], bfv, acc[mt][nt], 0, 0, 0);
        }
    }

    // epilogue: per-wave LDS transpose -> wide bf16 stores
    float* sw = sw_all + wave * (16 * 68);
    float bv[4];
#pragma unroll
    for (int nt = 0; nt < 4; nt++) bv[nt] = b_val[n0 + nt * 16 + row16];
    const int err = lane >> 2;          // read row 0..15
    const int ecs = (lane & 3) * 16;    // col segment

#pragma unroll
    for (int mt = 0; mt < 2; mt++) {
        __syncthreads();
#pragma unroll
        for (int nt = 0; nt < 4; nt++)
#pragma unroll
            for (int r = 0; r < 4; r++)
                sw[(rb4 + r) * 68 + nt * 16 + row16] = acc[mt][nt][r] + bv[nt];
        __syncthreads();
        const float* rp = sw + err * 68 + ecs;
        f32x4 v0 = ((const f32x4*)rp)[0];
        f32x4 v1 = ((const f32x4*)rp)[1];
        f32x4 v2 = ((const f32x4*)rp)[2];
        f32x4 v3 = ((const f32x4*)rp)[3];
        uint4 o0, o1;
        o0.x = pk2(v0[0], v0[1]); o0.y = pk2(v0[2], v0[3]);
        o0.z = pk2(v1[0], v1[1]); o0.w = pk2(v1[2], v1[3]);
        o1.x = pk2(v2[0], v2[1]); o1.y = pk2(v2[2], v2[3]);
        o1.z = pk2(v3[0], v3[1]); o1.w = pk2(v3[2], v3[3]);
        ushort_t* cp = C + (size_t)(r0 + mt * 16 + err) * 256 + n0 + ecs;
        ((uint4*)cp)[0] = o0;
        ((uint4*)cp)[1] = o1;
    }
}

// ======================= mega kernel =======================
// Per block: 16 queries. Phase A: offattn[16,384] = q @ woaT^T (MFMA, L2 B).
// Phase B: softmax + bilinear sampling from value_bf. Phase C:
// out[16,256] = mid @ woutT^T (MFMA, L2 B). offattn/mid never touch HBM.
__global__ __launch_bounds__(256) void msda_mega(
    const float* __restrict__ query, const float* __restrict__ refp,
    const ushort_t* __restrict__ value, const ushort_t* __restrict__ woaT,
    const float* __restrict__ bias_oa, const ushort_t* __restrict__ woutT,
    const float* __restrict__ b_out, float* __restrict__ out)
{
    constexpr int LVL_H[4]  = {64, 32, 16, 8};
    constexpr int LVL_W[4]  = {64, 32, 16, 8};
    constexpr int LVL_ST[4] = {0, 4096, 5120, 5376};

    __shared__ char smem[16 * 384 * 4];              // 24576 B
    float*    oa_s  = (float*)smem;                  // [16][384]
    ushort_t* mid_s = (ushort_t*)smem;               // [16][256] (alias, phased)

    const int tid  = threadIdx.x;
    const int wave = tid >> 6, lane = tid & 63;
    const int row16 = lane & 15, kg8 = (lane >> 4) * 8, rb4 = (lane >> 4) * 4;
    const int blk = blockIdx.x;
    const int q0  = blk * 16;
    const int b   = blk / 340;                       // 340 blocks per batch

    // ---------------- phase A: offattn = query @ woaT^T + bias ----------------
    {
        bf16x8 af[8];
        const float* qp = query + (size_t)(q0 + row16) * 256 + kg8;
#pragma unroll
        for (int kt = 0; kt < 8; kt++) {
            float4 f0 = *(const float4*)(qp + kt * 32);
            float4 f1 = *(const float4*)(qp + kt * 32 + 4);
            uint4 u;
            u.x = pk2(f0.x, f0.y); u.y = pk2(f0.z, f0.w);
            u.z = pk2(f1.x, f1.y); u.w = pk2(f1.z, f1.w);
            __builtin_memcpy(&af[kt], &u, 16);
        }
        f32x4 acc6[6] = {};
#pragma unroll
        for (int kt = 0; kt < 8; kt++)
#pragma unroll
            for (int nt = 0; nt < 6; nt++) {
                bf16x8 bfv = *(const bf16x8*)(woaT
                    + (size_t)(wave * 96 + nt * 16 + row16) * 256 + kt * 32 + kg8);
                acc6[nt] = __builtin_amdgcn_mfma_f32_16x16x32_bf16(
                    af[kt], bfv, acc6[nt], 0, 0, 0);
            }
#pragma unroll
        for (int nt = 0; nt < 6; nt++) {
            const int col = wave * 96 + nt * 16 + row16;
            const float bv = bias_oa[col];
#pragma unroll
            for (int r = 0; r < 4; r++)
                oa_s[(rb4 + r) * 384 + col] = acc6[nt][r] + bv;
        }
    }
    __syncthreads();

    // ---------------- phase B: softmax + sampling ----------------
    const int q    = tid >> 4;          // 0..15
    const int l16  = tid & 15;
    const int head = l16 >> 1;
    const int c16  = (l16 & 1) * 16;    // channel offset within head (0 or 16)

    // read this lane's logits + offsets from LDS into regs
    const float* lp = oa_s + q * 384 + 256 + head * 16;
    float lg[16];
#pragma unroll
    for (int j = 0; j < 16; j++) lg[j] = lp[j];
    float mx = lg[0];
#pragma unroll
    for (int j = 1; j < 16; j++) mx = fmaxf(mx, lg[j]);

    const float* op = oa_s + q * 384 + head * 32;
    float offs[32];
#pragma unroll
    for (int j = 0; j < 32; j++) offs[j] = op[j];

    const float* rpq = refp + (size_t)(q0 + q) * 8;
    float4 r0v = ((const float4*)rpq)[0];
    float4 r1v = ((const float4*)rpq)[1];
    const float rx[4] = {r0v.x, r0v.z, r1v.x, r1v.z};
    const float ry[4] = {r0v.y, r0v.w, r1v.y, r1v.w};

    __syncthreads();   // all oa_s reads complete -> safe to overwrite as mid_s

    const ushort_t* vbase = value + (size_t)b * LEN_IN * 256 + head * 32 + c16;

    float acc[16] = {};
    float esum = 0.f;

#pragma unroll
    for (int l = 0; l < 4; l++) {
        const int H = LVL_H[l], W = LVL_W[l], st = LVL_ST[l];
        const float fW = (float)W, fH = (float)H;
#pragma unroll
        for (int p = 0; p < 4; p++) {
            const float ox = offs[l * 8 + p * 2 + 0];
            const float oy = offs[l * 8 + p * 2 + 1];
            const float x = (rx[l] + ox / fW) * fW - 0.5f;
            const float y = (ry[l] + oy / fH) * fH - 0.5f;
            const float x0f = floorf(x), y0f = floorf(y);
            const float wx = x - x0f, wy = y - y0f;
            const int ix0 = (int)x0f, iy0 = (int)y0f;
            const int ix1 = ix0 + 1,  iy1 = iy0 + 1;
            const float vx0 = (ix0 >= 0 && ix0 < W) ? 1.f : 0.f;
            const float vx1 = (ix1 >= 0 && ix1 < W) ? 1.f : 0.f;
            const float vy0 = (iy0 >= 0 && iy0 < H) ? 1.f : 0.f;
            const float vy1 = (iy1 >= 0 && iy1 < H) ? 1.f : 0.f;
            const int cx0 = min(max(ix0, 0), W - 1);
            const int cx1 = min(max(ix1, 0), W - 1);
            const int cy0 = min(max(iy0, 0), H - 1);
            const int cy1 = min(max(iy1, 0), H - 1);
            const float hx0 = (1.f - wx) * vx0, hx1 = wx * vx1;
            const float hy0 = (1.f - wy) * vy0, hy1 = wy * vy1;

            const ushort_t* rp0 = vbase + (size_t)(st + cy0 * W) * 256;
            const ushort_t* rp1 = vbase + (size_t)(st + cy1 * W) * 256;
            const uint4* p00 = (const uint4*)(rp0 + (size_t)cx0 * 256);
            const uint4* p01 = (const uint4*)(rp0 + (size_t)cx1 * 256);
            const uint4* p10 = (const uint4*)(rp1 + (size_t)cx0 * 256);
            const uint4* p11 = (const uint4*)(rp1 + (size_t)cx1 * 256);
            uint4 a00 = p00[0], b00 = p00[1];
            uint4 a01 = p01[0], b01 = p01[1];
            uint4 a10 = p10[0], b10 = p10[1];
            uint4 a11 = p11[0], b11 = p11[1];

            const float e = __expf(lg[l * 4 + p] - mx);
            esum += e;
            const float w00 = e * hx0 * hy0, w01 = e * hx1 * hy0;
            const float w10 = e * hx0 * hy1, w11 = e * hx1 * hy1;

            const unsigned* pa[4] = {&a00.x, &a01.x, &a10.x, &a11.x};
            const unsigned* pb[4] = {&b00.x, &b01.x, &b10.x, &b11.x};
            const float     wc[4] = {w00, w01, w10, w11};
#pragma unroll
            for (int cr = 0; cr < 4; cr++) {
                const float w = wc[cr];
#pragma unroll
                for (int d = 0; d < 4; d++) {
                    unsigned u = pa[cr][d];
                    acc[2 * d]     = fmaf(w, __uint_as_float(u << 16), acc[2 * d]);
                    acc[2 * d + 1] = fmaf(w, __uint_as_float(u & 0xFFFF0000u), acc[2 * d + 1]);
                    u = pb[cr][d];
                    acc[8 + 2 * d]     = fmaf(w, __uint_as_float(u << 16), acc[8 + 2 * d]);
                    acc[8 + 2 * d + 1] = fmaf(w, __uint_as_float(u & 0xFFFF0000u), acc[8 + 2 * d + 1]);
                }
            }
        }
    }

    {
        const float inv = 1.f / esum;
        uint4 o0, o1;
        o0.x = pk2(acc[0] * inv, acc[1] * inv);
        o0.y = pk2(acc[2] * inv, acc[3] * inv);
        o0.z = pk2(acc[4] * inv, acc[5] * inv);
        o0.w = pk2(acc[6] * inv, acc[7] * inv);
        o1.x = pk2(acc[8] * inv, acc[9] * inv);
        o1.y = pk2(acc[10] * inv, acc[11] * inv);
        o1.z = pk2(acc[12] * inv, acc[13] * inv);
        o1.w = pk2(acc[14] * inv, acc[15] * inv);
        uint4* mp = (uint4*)(mid_s + q * 256 + head * 32 + c16);
        mp[0] = o0;
        mp[1] = o1;
    }
    __syncthreads();

    // ---------------- phase C: out = mid @ woutT^T + b_out ----------------
    {
        bf16x8 am[8];
#pragma unroll
        for (int kt = 0; kt < 8; kt++)
            am[kt] = *(const bf16x8*)(mid_s + row16 * 256 + kt * 32 + kg8);
        f32x4 acc4[4] = {};
#pragma unroll
        for (int kt = 0; kt < 8; kt++)
#pragma unroll
            for (int nt = 0; nt < 4; nt++) {
                bf16x8 bfv = *(const bf16x8*)(woutT
                    + (size_t)(wave * 64 + nt * 16 + row16) * 256 + kt * 32 + kg8);
                acc4[nt] = __builtin_amdgcn_mfma_f32_16x16x32_bf16(
                    am[kt], bfv, acc4[nt], 0, 0, 0);
            }
#pragma unroll
        for (int nt = 0; nt < 4; nt++) {
            const int col = wave * 64 + nt * 16 + row16;
            const float bv = b_out[col];
#pragma unroll
            for (int r = 0; r < 4; r++)
                out[(size_t)(q0 + rb4 + r) * 256 + col] = acc4[nt][r] + bv;
        }
    }
}

// ======================= launch =======================
extern "C" void kernel_launch(void* const* d_in, const int* in_sizes, int n_in,
                              void* d_out, int out_size, void* d_ws, size_t ws_size,
                              hipStream_t stream)
{
    const float* query  = (const float*)d_in[0];
    const float* refp   = (const float*)d_in[1];
    const float* inflat = (const float*)d_in[2];
    const float* W_val  = (const float*)d_in[5];
    const float* b_val  = (const float*)d_in[6];
    const float* W_off  = (const float*)d_in[7];
    const float* b_off  = (const float*)d_in[8];
    const float* W_attn = (const float*)d_in[9];
    const float* b_attn = (const float*)d_in[10];
    const float* W_out  = (const float*)d_in[11];
    const float* b_out  = (const float*)d_in[12];
    float* out = (float*)d_out;

    char* ws = (char*)d_ws;
    ushort_t* value_bf = (ushort_t*)ws;                    // 11,141,120
    ushort_t* wvT      = (ushort_t*)(ws + 11141120);       // 131,072
    ushort_t* woutT    = (ushort_t*)(ws + 11272192);       // 131,072
    ushort_t* woaT     = (ushort_t*)(ws + 11403264);       // 196,608
    float*    bias_oa  = (float*)   (ws + 11599872);       // 1,536

    pack_w<<<dim3(113), dim3(256), 0, stream>>>(
        W_val, W_off, W_attn, W_out, b_off, b_attn, wvT, woaT, woutT, bias_oa);
    gemm_value<<<dim3(680), dim3(256), 0, stream>>>(
        inflat, wvT, b_val, value_bf);
    msda_mega<<<dim3(M_TOT / 16), dim3(256), 0, stream>>>(
        query, refp, value_bf, woaT, bias_oa, woutT, b_out, out);
}